// Round 13
// baseline (488.298 us; speedup 1.0000x reference)
//
#include <hip/hip_runtime.h>
#include <hip/hip_bf16.h>

typedef __attribute__((ext_vector_type(4))) unsigned short u16x4;
typedef __attribute__((ext_vector_type(8))) short short8;
typedef __attribute__((ext_vector_type(4))) short short4b;
typedef __attribute__((ext_vector_type(4))) float f32x4;

__device__ inline unsigned short f2bf(float f) {
    union { float f; unsigned int i; } v; v.f = f;
    unsigned int r = v.i + 0x7fffu + ((v.i >> 16) & 1u);
    return (unsigned short)(r >> 16);
}

// pack 2 f32 -> 2 bf16 in one u32 (v_cvt_pk_bf16_f32)
__device__ inline unsigned int pk_bf16(float a, float b) {
    union { __hip_bfloat162 h; unsigned int u; } cv;
    cv.h = __float22bfloat162_rn(float2{a, b});
    return cv.u;
}

#define MFMA_PV(a, b, c) __builtin_amdgcn_mfma_f32_16x16x16bf16_1k((a), (b), (c), 0, 0, 0)
#define MFMA32(a, b, c) __builtin_amdgcn_mfma_f32_16x16x32_bf16((a), (b), (c), 0, 0, 0)

// exp(s*0.125) == exp2(s * 0.125*log2(e))
#define SCL 0.18033688011112042f

__device__ inline void gload_lds16(const unsigned short* g, unsigned short* l) {
    __builtin_amdgcn_global_load_lds(
        (const __attribute__((address_space(1))) void*)g,
        (__attribute__((address_space(3))) void*)l,
        16, 0, 0);
}

// ---------------------------------------------------------------------------
// 3 input converts fused (uniform path): f32 -> bf16, grid 24576
// ---------------------------------------------------------------------------
__global__ __launch_bounds__(256) void convert3(const float* __restrict__ q,
                                                const float* __restrict__ k,
                                                const float* __restrict__ v,
                                                unsigned short* __restrict__ Xq,
                                                unsigned short* __restrict__ Xk,
                                                unsigned short* __restrict__ Xv) {
    int bid = blockIdx.x;
    const float* in = (bid < 8192) ? q : (bid < 16384) ? k : v;
    unsigned short* out = (bid < 8192) ? Xq : (bid < 16384) ? Xk : Xv;
    int i = (bid & 8191) * 256 + threadIdx.x;
    float4 vv = ((const float4*)in)[i];
    u16x4 o = { f2bf(vv.x), f2bf(vv.y), f2bf(vv.z), f2bf(vv.w) };
    ((u16x4*)out)[i] = o;
}

// ---------------------------------------------------------------------------
// 4 weight transposes fused: out_bf16[n][k] = in_f32[k][n], grid (32,32,4)
// ---------------------------------------------------------------------------
__global__ __launch_bounds__(256) void transpose_w4(const float* __restrict__ W0,
                                                    const float* __restrict__ W1,
                                                    const float* __restrict__ W2,
                                                    const float* __restrict__ W3,
                                                    unsigned short* __restrict__ O0,
                                                    unsigned short* __restrict__ O1,
                                                    unsigned short* __restrict__ O2,
                                                    unsigned short* __restrict__ O3) {
    __shared__ unsigned short tile[32][33];
    const float* in = (blockIdx.z == 0) ? W0 : (blockIdx.z == 1) ? W1
                    : (blockIdx.z == 2) ? W2 : W3;
    unsigned short* out = (blockIdx.z == 0) ? O0 : (blockIdx.z == 1) ? O1
                        : (blockIdx.z == 2) ? O2 : O3;
    int c0 = blockIdx.x * 32, r0 = blockIdx.y * 32;
    int x = threadIdx.x & 31, y = threadIdx.x >> 5;
#pragma unroll
    for (int i = 0; i < 4; i++)
        tile[y + i * 8][x] = f2bf(in[(size_t)(r0 + y + i * 8) * 1024 + c0 + x]);
    __syncthreads();
#pragma unroll
    for (int i = 0; i < 4; i++)
        out[(size_t)(c0 + y + i * 8) * 1024 + r0 + x] = tile[x][y + i * 8];
}

// ---------------------------------------------------------------------------
// GEMM (m97 structure + T2 via pre-swizzled source).
// F32OUT: nontemporal f32 out. KTILED: attn tile+swizzle K layout.
// VTILED: attn V tile layout [bh][itk][ks][d][key16].
// ---------------------------------------------------------------------------
template <int F32OUT, int KTILED, int VTILED>
__global__ __launch_bounds__(256) void gemm_bt(const unsigned short* __restrict__ X,
                                               const unsigned short* __restrict__ Wt,
                                               const float* __restrict__ bias,
                                               void* __restrict__ outp,
                                               int M, int N, int K) {
    __shared__ unsigned short As[128 * 64];
    __shared__ unsigned short Bs[128 * 64];
    const int t = threadIdx.x;
    const int l = t & 63, w = t >> 6;
    const int lg = l >> 4, ln = l & 15;
    const int wm = (w >> 1) * 64, wn = (w & 1) * 64;
    const int m0 = blockIdx.y * 128, n0 = blockIdx.x * 128;

    const f32x4 zero = {0.f, 0.f, 0.f, 0.f};
    f32x4 acc[4][4];
#pragma unroll
    for (int i = 0; i < 4; i++)
#pragma unroll
        for (int j = 0; j < 4; j++) acc[i][j] = zero;

    int sr[4], sc[4];
#pragma unroll
    for (int i = 0; i < 4; i++) {
        int pos = i * 2048 + t * 8;
        sr[i] = pos >> 6;
        int c8 = (pos >> 3) & 7;
        sc[i] = (c8 ^ (sr[i] & 7)) * 8;
    }

    for (int k0 = 0; k0 < K; k0 += 64) {
#pragma unroll
        for (int i = 0; i < 4; i++)
            gload_lds16(&X[(size_t)(m0 + sr[i]) * K + k0 + sc[i]], &As[i * 2048 + w * 512]);
#pragma unroll
        for (int i = 0; i < 4; i++)
            gload_lds16(&Wt[(size_t)(n0 + sr[i]) * K + k0 + sc[i]], &Bs[i * 2048 + w * 512]);
        __syncthreads();
#pragma unroll
        for (int kk = 0; kk < 2; kk++) {
            short8 af[4], bfr[4];
#pragma unroll
            for (int i = 0; i < 4; i++) {
                int sl = (((kk << 2) | lg) ^ (ln & 7)) * 8;
                af[i]  = *(const short8*)&As[(wm + i * 16 + ln) * 64 + sl];
                bfr[i] = *(const short8*)&Bs[(wn + i * 16 + ln) * 64 + sl];
            }
#pragma unroll
            for (int i = 0; i < 4; i++)
#pragma unroll
                for (int j = 0; j < 4; j++)
                    acc[i][j] = MFMA32(af[i], bfr[j], acc[i][j]);
        }
        __syncthreads();
    }

#pragma unroll
    for (int j = 0; j < 4; j++) {
        int gn = n0 + wn + j * 16 + ln;
        float bvv = bias[gn];
#pragma unroll
        for (int i = 0; i < 4; i++) {
            int gm = m0 + wm + i * 16 + 4 * lg;
#pragma unroll
            for (int jj = 0; jj < 4; jj++) {
                float val = acc[i][j][jj] + bvv;
                int m = gm + jj, n = gn;
                if (F32OUT) {
                    __builtin_nontemporal_store(val,
                        &((float*)outp)[(size_t)m * N + n]);
                } else if (KTILED) {
                    int b = m >> 11, s = m & 2047;
                    int itk = s >> 5, r = s & 31;
                    int h = n >> 6, dl = n & 63;
                    int cst = (dl >> 3) ^ (r & 7);
                    size_t off = (size_t)(b * 16 + h) * 131072 +
                                 (size_t)itk * 2048 + r * 64 + cst * 8 + (dl & 7);
                    ((unsigned short*)outp)[off] = f2bf(val);
                } else if (VTILED) {
                    int b = m >> 11, s = m & 2047;
                    int h = n >> 6, dl = n & 63;
                    size_t off = (size_t)(b * 16 + h) * 131072 +
                                 (size_t)(s >> 5) * 2048 + ((s >> 4) & 1) * 1024 +
                                 dl * 16 + (s & 15);
                    ((unsigned short*)outp)[off] = f2bf(val);
                } else {
                    ((unsigned short*)outp)[(size_t)m * N + n] = f2bf(val);
                }
            }
        }
    }
}

// ---------------------------------------------------------------------------
// Fused attention. Block = (b,h) x 64 q-rows; wave w owns 16 q-rows.
// ONE 32KB LDS buffer overlaid across passes (occupancy 5 blocks/CU):
//   pass1 (KVBLK=128): K dbuf at {0, 8192}
//   pass2 (KVBLK=64):  K dbuf at {0, 4096}, V dbuf at {8192, 12288}
// Pass2 keeps the counted vmcnt(4) barrier (staged loads land, NT attn
// stores stay in flight).
// ---------------------------------------------------------------------------
__global__ __launch_bounds__(256) void attn_fused(const unsigned short* __restrict__ Qp,
                                                  const unsigned short* __restrict__ Kt,
                                                  const unsigned short* __restrict__ Vt,
                                                  float* __restrict__ attn_out,
                                                  unsigned short* __restrict__ Ctx) {
    const int S = 2048, Dm = 1024;
    __shared__ unsigned short smem[16384];   // 32 KB, pass-overlaid

    int blk = blockIdx.x;
    int wid = (blk & 7) * 256 + (blk >> 3);   // XCD swizzle (2048 % 8 == 0)
    int qt = wid & 31, bh = wid >> 5;
    int b = bh >> 4, h = bh & 15;
    int t = threadIdx.x, l = t & 63, w = t >> 6;
    int lg = l >> 4, ln = l & 15;
    int q0 = qt * 64 + w * 16;

    const unsigned short* Qrow = Qp + (size_t)(b * S + q0 + ln) * Dm + h * 64;
    short8 qf0 = *(const short8*)&Qrow[8 * lg];
    short8 qf1 = *(const short8*)&Qrow[32 + 8 * lg];

    const unsigned short* Kb = Kt + (size_t)bh * 131072;
    const unsigned short* Vb = Vt + (size_t)bh * 131072;

    const int c0x = ((0 * 4 + lg) ^ (ln & 7)) * 8;
    const int c1x = ((1 * 4 + lg) ^ (ln & 7)) * 8;

    const f32x4 zero = {0.f, 0.f, 0.f, 0.f};

    // ---- pass 1: softmax denominator, KVBLK=128, K dbuf {0, 8192} ----
    float se = 0.f;
    {
#define STAGE_K128(it, buf) do { \
    gload_lds16(Kb + (size_t)(it) * 8192 + t * 8, &smem[(buf) * 8192 + w * 512]); \
    gload_lds16(Kb + (size_t)(it) * 8192 + 2048 + t * 8, &smem[(buf) * 8192 + 2048 + w * 512]); \
    gload_lds16(Kb + (size_t)(it) * 8192 + 4096 + t * 8, &smem[(buf) * 8192 + 4096 + w * 512]); \
    gload_lds16(Kb + (size_t)(it) * 8192 + 6144 + t * 8, &smem[(buf) * 8192 + 6144 + w * 512]); } while (0)
        int cur = 0;
        STAGE_K128(0, 0);
        __syncthreads();
        for (int it = 0; it < 16; ++it) {
            if (it < 15) STAGE_K128(it + 1, cur ^ 1);
            f32x4 s[8];
            __builtin_amdgcn_s_setprio(1);
#pragma unroll
            for (int g = 0; g < 8; g++) {
                int gbase = cur * 8192 + (g >> 1) * 2048 + (g & 1) * 1024 + ln * 64;
                s[g] = MFMA32(*(const short8*)&smem[gbase + c0x], qf0, zero);
                s[g] = MFMA32(*(const short8*)&smem[gbase + c1x], qf1, s[g]);
            }
            __builtin_amdgcn_s_setprio(0);
#pragma unroll
            for (int g = 0; g < 8; g++)
                se += exp2f(s[g][0] * SCL) + exp2f(s[g][1] * SCL) +
                      exp2f(s[g][2] * SCL) + exp2f(s[g][3] * SCL);
            __syncthreads();
            cur ^= 1;
        }
#undef STAGE_K128
    }
    se += __shfl_xor(se, 16);
    se += __shfl_xor(se, 32);
    float nlse = -log2f(se);

    // ---- pass 2: attn write (f32 NT) + PV; K dbuf {0,4096}, V dbuf {8192,12288} ----
    const int gb0 = 0 * 2048 + 0 * 1024 + ln * 64;
    const int gb1 = 0 * 2048 + 1 * 1024 + ln * 64;   // note: within 4096-elem K buf
    const int gb2 = 1 * 2048 + 0 * 1024 + ln * 64;
    const int gb3 = 1 * 2048 + 1 * 1024 + ln * 64;

#define STAGE_K64(it, buf) do { \
    gload_lds16(Kb + (size_t)(it) * 4096 + t * 8, &smem[(buf) * 4096 + w * 512]); \
    gload_lds16(Kb + (size_t)(it) * 4096 + 2048 + t * 8, &smem[(buf) * 4096 + 2048 + w * 512]); } while (0)
#define STAGE_V64(it, buf) do { \
    gload_lds16(Vb + (size_t)(it) * 4096 + t * 8, &smem[8192 + (buf) * 4096 + w * 512]); \
    gload_lds16(Vb + (size_t)(it) * 4096 + 2048 + t * 8, &smem[8192 + (buf) * 4096 + 2048 + w * 512]); } while (0)

    f32x4 acc[4];
#pragma unroll
    for (int i = 0; i < 4; i++) acc[i] = zero;

    float* Arow = attn_out + ((size_t)bh * S + q0 + ln) * S;

    int cur = 0;
    STAGE_K64(0, 0);
    STAGE_V64(0, 0);
    __syncthreads();
    for (int it = 0; it < 32; ++it) {
        if (it < 31) { STAGE_K64(it + 1, cur ^ 1); STAGE_V64(it + 1, cur ^ 1); }
        // pin issue order: the 4 staged loads above must precede the NT stores
        __builtin_amdgcn_sched_barrier(0);
        int kbase = cur * 4096;
        f32x4 s[4];
        __builtin_amdgcn_s_setprio(1);
        s[0] = MFMA32(*(const short8*)&smem[kbase + gb0 + c0x], qf0, zero);
        s[0] = MFMA32(*(const short8*)&smem[kbase + gb0 + c1x], qf1, s[0]);
        s[1] = MFMA32(*(const short8*)&smem[kbase + gb1 + c0x], qf0, zero);
        s[1] = MFMA32(*(const short8*)&smem[kbase + gb1 + c1x], qf1, s[1]);
        s[2] = MFMA32(*(const short8*)&smem[kbase + gb2 + c0x], qf0, zero);
        s[2] = MFMA32(*(const short8*)&smem[kbase + gb2 + c1x], qf1, s[2]);
        s[3] = MFMA32(*(const short8*)&smem[kbase + gb3 + c0x], qf0, zero);
        s[3] = MFMA32(*(const short8*)&smem[kbase + gb3 + c1x], qf1, s[3]);
        __builtin_amdgcn_s_setprio(0);

        union { short4b v; unsigned int u2[2]; } pf[4];
#pragma unroll
        for (int g = 0; g < 4; g++) {
            f32x4 pw;
#pragma unroll
            for (int j = 0; j < 4; j++)
                pw[j] = exp2f(fmaf(s[g][j], SCL, nlse));
            pf[g].u2[0] = pk_bf16(pw[0], pw[1]);
            pf[g].u2[1] = pk_bf16(pw[2], pw[3]);
            __builtin_nontemporal_store(pw, (f32x4*)&Arow[it * 64 + g * 16 + 4 * lg]);
        }

        int vbase0 = 8192 + cur * 4096;
        __builtin_amdgcn_s_setprio(1);
#pragma unroll
        for (int db = 0; db < 4; db++) {
            int vbase = vbase0 + (db * 16 + ln) * 16 + 4 * lg;
            acc[db] = MFMA_PV(pf[0].v, *(const short4b*)&smem[vbase], acc[db]);
            acc[db] = MFMA_PV(pf[1].v, *(const short4b*)&smem[vbase + 1024], acc[db]);
            acc[db] = MFMA_PV(pf[2].v, *(const short4b*)&smem[vbase + 2048], acc[db]);
            acc[db] = MFMA_PV(pf[3].v, *(const short4b*)&smem[vbase + 3072], acc[db]);
        }
        __builtin_amdgcn_s_setprio(0);
        // counted drain: 4 loads (oldest) must land; 4 NT stores may fly on
        asm volatile("s_waitcnt vmcnt(4)\n\ts_barrier" ::: "memory");
        cur ^= 1;
    }

    // ctx: lane reg j holds (q = q0 + 4*lg + j, d = db*16 + ln)
#pragma unroll
    for (int db = 0; db < 4; db++)
#pragma unroll
        for (int j = 0; j < 4; j++)
            Ctx[(size_t)(b * S + q0 + 4 * lg + j) * Dm + h * 64 + db * 16 + ln] =
                f2bf(acc[db][j]);
#undef STAGE_K64
#undef STAGE_V64
}

// ---------------------------------------------------------------------------
extern "C" void kernel_launch(void* const* d_in, const int* in_sizes, int n_in,
                              void* d_out, int out_size, void* d_ws, size_t ws_size,
                              hipStream_t stream) {
    const float* query = (const float*)d_in[0];
    const float* key_  = (const float*)d_in[1];
    const float* value = (const float*)d_in[2];
    const float* Wq = (const float*)d_in[4];
    const float* bq = (const float*)d_in[5];
    const float* Wk = (const float*)d_in[6];
    const float* bk = (const float*)d_in[7];
    const float* Wv = (const float*)d_in[8];
    const float* bv = (const float*)d_in[9];
    const float* Wo = (const float*)d_in[10];
    const float* bo = (const float*)d_in[11];

    const size_t BSD = (size_t)4 * 2048 * 1024;
    const size_t DD  = (size_t)1024 * 1024;

    unsigned short* Xq  = (unsigned short*)d_ws;
    unsigned short* Xk  = Xq + BSD;
    unsigned short* Xv  = Xk + BSD;
    unsigned short* Qp  = Xv + BSD;
    unsigned short* Kt  = Qp + BSD;                 // K tiled+swizzled
    unsigned short* Vt  = Kt + BSD;                 // V tiled (direct from GEMM)
    unsigned short* WqT = Vt + BSD;
    unsigned short* WkT = WqT + DD;
    unsigned short* WvT = WkT + DD;
    unsigned short* WoT = WvT + DD;
    unsigned short* Ctx = Xq;                       // dead after Q-GEMM

    float* out0 = (float*)d_out;                    // [B,S,D] f32
    float* attn = out0 + BSD;                       // [B,H,S,S] f32

    dim3 tb(256);

    convert3<<<dim3(24576), tb, 0, stream>>>(query, key_, value, Xq, Xk, Xv);
    transpose_w4<<<dim3(32, 32, 4), tb, 0, stream>>>(Wq, Wk, Wv, Wo, WqT, WkT, WvT, WoT);

    gemm_bt<0, 0, 0><<<dim3(8, 64), tb, 0, stream>>>(Xq, WqT, bq, Qp, 8192, 1024, 1024);
    gemm_bt<0, 1, 0><<<dim3(8, 64), tb, 0, stream>>>(Xk, WkT, bk, Kt, 8192, 1024, 1024);
    gemm_bt<0, 0, 1><<<dim3(8, 64), tb, 0, stream>>>(Xv, WvT, bv, Vt, 8192, 1024, 1024);

    attn_fused<<<dim3(2048), tb, 0, stream>>>(Qp, Kt, Vt, attn, Ctx);

    gemm_bt<1, 0, 0><<<dim3(8, 64), tb, 0, stream>>>(Ctx, WoT, bo, out0, 8192, 1024, 1024);
}

// Round 14
// 459.798 us; speedup vs baseline: 1.0620x; 1.0620x over previous
//
#include <hip/hip_runtime.h>
#include <hip/hip_bf16.h>

typedef __attribute__((ext_vector_type(4))) unsigned short u16x4;
typedef __attribute__((ext_vector_type(8))) short short8;
typedef __attribute__((ext_vector_type(4))) short short4b;
typedef __attribute__((ext_vector_type(4))) float f32x4;

__device__ inline unsigned short f2bf(float f) {
    union { float f; unsigned int i; } v; v.f = f;
    unsigned int r = v.i + 0x7fffu + ((v.i >> 16) & 1u);
    return (unsigned short)(r >> 16);
}

// pack 2 f32 -> 2 bf16 in one u32 (v_cvt_pk_bf16_f32)
__device__ inline unsigned int pk_bf16(float a, float b) {
    union { __hip_bfloat162 h; unsigned int u; } cv;
    cv.h = __float22bfloat162_rn(float2{a, b});
    return cv.u;
}

#define MFMA_PV(a, b, c) __builtin_amdgcn_mfma_f32_16x16x16bf16_1k((a), (b), (c), 0, 0, 0)
#define MFMA32(a, b, c) __builtin_amdgcn_mfma_f32_16x16x32_bf16((a), (b), (c), 0, 0, 0)

// exp(s*0.125) == exp2(s * 0.125*log2(e))
#define SCL 0.18033688011112042f

__device__ inline void gload_lds16(const unsigned short* g, unsigned short* l) {
    __builtin_amdgcn_global_load_lds(
        (const __attribute__((address_space(1))) void*)g,
        (__attribute__((address_space(3))) void*)l,
        16, 0, 0);
}

// ---------------------------------------------------------------------------
// 3 input converts fused (uniform path): f32 -> bf16, grid 24576
// ---------------------------------------------------------------------------
__global__ __launch_bounds__(256) void convert3(const float* __restrict__ q,
                                                const float* __restrict__ k,
                                                const float* __restrict__ v,
                                                unsigned short* __restrict__ Xq,
                                                unsigned short* __restrict__ Xk,
                                                unsigned short* __restrict__ Xv) {
    int bid = blockIdx.x;
    const float* in = (bid < 8192) ? q : (bid < 16384) ? k : v;
    unsigned short* out = (bid < 8192) ? Xq : (bid < 16384) ? Xk : Xv;
    int i = (bid & 8191) * 256 + threadIdx.x;
    float4 vv = ((const float4*)in)[i];
    u16x4 o = { f2bf(vv.x), f2bf(vv.y), f2bf(vv.z), f2bf(vv.w) };
    ((u16x4*)out)[i] = o;
}

// ---------------------------------------------------------------------------
// 4 weight transposes fused: out_bf16[n][k] = in_f32[k][n], grid (32,32,4)
// ---------------------------------------------------------------------------
__global__ __launch_bounds__(256) void transpose_w4(const float* __restrict__ W0,
                                                    const float* __restrict__ W1,
                                                    const float* __restrict__ W2,
                                                    const float* __restrict__ W3,
                                                    unsigned short* __restrict__ O0,
                                                    unsigned short* __restrict__ O1,
                                                    unsigned short* __restrict__ O2,
                                                    unsigned short* __restrict__ O3) {
    __shared__ unsigned short tile[32][33];
    const float* in = (blockIdx.z == 0) ? W0 : (blockIdx.z == 1) ? W1
                    : (blockIdx.z == 2) ? W2 : W3;
    unsigned short* out = (blockIdx.z == 0) ? O0 : (blockIdx.z == 1) ? O1
                        : (blockIdx.z == 2) ? O2 : O3;
    int c0 = blockIdx.x * 32, r0 = blockIdx.y * 32;
    int x = threadIdx.x & 31, y = threadIdx.x >> 5;
#pragma unroll
    for (int i = 0; i < 4; i++)
        tile[y + i * 8][x] = f2bf(in[(size_t)(r0 + y + i * 8) * 1024 + c0 + x]);
    __syncthreads();
#pragma unroll
    for (int i = 0; i < 4; i++)
        out[(size_t)(c0 + y + i * 8) * 1024 + r0 + x] = tile[x][y + i * 8];
}

// ---------------------------------------------------------------------------
// GEMM (m97 structure + T2 via pre-swizzled source).
// F32OUT: nontemporal f32 out. KTILED: attn tile+swizzle K layout.
// VTILED: attn V tile layout [bh][itk][ks][d][key16].
// ---------------------------------------------------------------------------
template <int F32OUT, int KTILED, int VTILED>
__global__ __launch_bounds__(256) void gemm_bt(const unsigned short* __restrict__ X,
                                               const unsigned short* __restrict__ Wt,
                                               const float* __restrict__ bias,
                                               void* __restrict__ outp,
                                               int M, int N, int K) {
    __shared__ unsigned short As[128 * 64];
    __shared__ unsigned short Bs[128 * 64];
    const int t = threadIdx.x;
    const int l = t & 63, w = t >> 6;
    const int lg = l >> 4, ln = l & 15;
    const int wm = (w >> 1) * 64, wn = (w & 1) * 64;
    const int m0 = blockIdx.y * 128, n0 = blockIdx.x * 128;

    const f32x4 zero = {0.f, 0.f, 0.f, 0.f};
    f32x4 acc[4][4];
#pragma unroll
    for (int i = 0; i < 4; i++)
#pragma unroll
        for (int j = 0; j < 4; j++) acc[i][j] = zero;

    int sr[4], sc[4];
#pragma unroll
    for (int i = 0; i < 4; i++) {
        int pos = i * 2048 + t * 8;
        sr[i] = pos >> 6;
        int c8 = (pos >> 3) & 7;
        sc[i] = (c8 ^ (sr[i] & 7)) * 8;
    }

    for (int k0 = 0; k0 < K; k0 += 64) {
#pragma unroll
        for (int i = 0; i < 4; i++)
            gload_lds16(&X[(size_t)(m0 + sr[i]) * K + k0 + sc[i]], &As[i * 2048 + w * 512]);
#pragma unroll
        for (int i = 0; i < 4; i++)
            gload_lds16(&Wt[(size_t)(n0 + sr[i]) * K + k0 + sc[i]], &Bs[i * 2048 + w * 512]);
        __syncthreads();
#pragma unroll
        for (int kk = 0; kk < 2; kk++) {
            short8 af[4], bfr[4];
#pragma unroll
            for (int i = 0; i < 4; i++) {
                int sl = (((kk << 2) | lg) ^ (ln & 7)) * 8;
                af[i]  = *(const short8*)&As[(wm + i * 16 + ln) * 64 + sl];
                bfr[i] = *(const short8*)&Bs[(wn + i * 16 + ln) * 64 + sl];
            }
#pragma unroll
            for (int i = 0; i < 4; i++)
#pragma unroll
                for (int j = 0; j < 4; j++)
                    acc[i][j] = MFMA32(af[i], bfr[j], acc[i][j]);
        }
        __syncthreads();
    }

#pragma unroll
    for (int j = 0; j < 4; j++) {
        int gn = n0 + wn + j * 16 + ln;
        float bvv = bias[gn];
#pragma unroll
        for (int i = 0; i < 4; i++) {
            int gm = m0 + wm + i * 16 + 4 * lg;
#pragma unroll
            for (int jj = 0; jj < 4; jj++) {
                float val = acc[i][j][jj] + bvv;
                int m = gm + jj, n = gn;
                if (F32OUT) {
                    __builtin_nontemporal_store(val,
                        &((float*)outp)[(size_t)m * N + n]);
                } else if (KTILED) {
                    int b = m >> 11, s = m & 2047;
                    int itk = s >> 5, r = s & 31;
                    int h = n >> 6, dl = n & 63;
                    int cst = (dl >> 3) ^ (r & 7);
                    size_t off = (size_t)(b * 16 + h) * 131072 +
                                 (size_t)itk * 2048 + r * 64 + cst * 8 + (dl & 7);
                    ((unsigned short*)outp)[off] = f2bf(val);
                } else if (VTILED) {
                    int b = m >> 11, s = m & 2047;
                    int h = n >> 6, dl = n & 63;
                    size_t off = (size_t)(b * 16 + h) * 131072 +
                                 (size_t)(s >> 5) * 2048 + ((s >> 4) & 1) * 1024 +
                                 dl * 16 + (s & 15);
                    ((unsigned short*)outp)[off] = f2bf(val);
                } else {
                    ((unsigned short*)outp)[(size_t)m * N + n] = f2bf(val);
                }
            }
        }
    }
}

// ---------------------------------------------------------------------------
// Fused attention. Block = (b,h) x 64 q-rows; wave w owns 16 q-rows.
// Pass1: KVBLK=128 (16 iters, Ks[2][8192]). Pass2: KVBLK=64, counted
// vmcnt(4) barrier (4 staged loads land, 4 NT attn stores stay in flight).
// 48 KB LDS -> 3 blocks/CU: the measured sweet spot (32 KB/5 blocks and
// larger QBLK variants both regressed).
// ---------------------------------------------------------------------------
__global__ __launch_bounds__(256) void attn_fused(const unsigned short* __restrict__ Qp,
                                                  const unsigned short* __restrict__ Kt,
                                                  const unsigned short* __restrict__ Vt,
                                                  float* __restrict__ attn_out,
                                                  unsigned short* __restrict__ Ctx) {
    const int S = 2048, Dm = 1024;
    __shared__ unsigned short Ks[2][8192];   // pass1: 128-key tiles; pass2 uses [2][4096] halves
    __shared__ unsigned short Vs[2][4096];

    int blk = blockIdx.x;
    int wid = (blk & 7) * 256 + (blk >> 3);   // XCD swizzle (2048 % 8 == 0)
    int qt = wid & 31, bh = wid >> 5;
    int b = bh >> 4, h = bh & 15;
    int t = threadIdx.x, l = t & 63, w = t >> 6;
    int lg = l >> 4, ln = l & 15;
    int q0 = qt * 64 + w * 16;

    const unsigned short* Qrow = Qp + (size_t)(b * S + q0 + ln) * Dm + h * 64;
    short8 qf0 = *(const short8*)&Qrow[8 * lg];
    short8 qf1 = *(const short8*)&Qrow[32 + 8 * lg];

    const unsigned short* Kb = Kt + (size_t)bh * 131072;
    const unsigned short* Vb = Vt + (size_t)bh * 131072;

    const int c0x = ((0 * 4 + lg) ^ (ln & 7)) * 8;
    const int c1x = ((1 * 4 + lg) ^ (ln & 7)) * 8;

    const f32x4 zero = {0.f, 0.f, 0.f, 0.f};

    // ---- pass 1: softmax denominator, KVBLK=128 ----
    float se = 0.f;
    {
#define STAGE_K128(it, buf) do { \
    gload_lds16(Kb + (size_t)(it) * 8192 + t * 8, &Ks[buf][w * 512]); \
    gload_lds16(Kb + (size_t)(it) * 8192 + 2048 + t * 8, &Ks[buf][2048 + w * 512]); \
    gload_lds16(Kb + (size_t)(it) * 8192 + 4096 + t * 8, &Ks[buf][4096 + w * 512]); \
    gload_lds16(Kb + (size_t)(it) * 8192 + 6144 + t * 8, &Ks[buf][6144 + w * 512]); } while (0)
        int cur = 0;
        STAGE_K128(0, 0);
        __syncthreads();
        for (int it = 0; it < 16; ++it) {
            if (it < 15) STAGE_K128(it + 1, cur ^ 1);
            f32x4 s[8];
            __builtin_amdgcn_s_setprio(1);
#pragma unroll
            for (int g = 0; g < 8; g++) {
                int gbase = (g >> 1) * 2048 + (g & 1) * 1024 + ln * 64;
                s[g] = MFMA32(*(const short8*)&Ks[cur][gbase + c0x], qf0, zero);
                s[g] = MFMA32(*(const short8*)&Ks[cur][gbase + c1x], qf1, s[g]);
            }
            __builtin_amdgcn_s_setprio(0);
#pragma unroll
            for (int g = 0; g < 8; g++)
                se += exp2f(s[g][0] * SCL) + exp2f(s[g][1] * SCL) +
                      exp2f(s[g][2] * SCL) + exp2f(s[g][3] * SCL);
            __syncthreads();
            cur ^= 1;
        }
#undef STAGE_K128
    }
    se += __shfl_xor(se, 16);
    se += __shfl_xor(se, 32);
    float nlse = -log2f(se);

    // ---- pass 2: attn write (f32 NT) + PV, counted-vmcnt barrier ----
    const int gb0 = 0 * 2048 + 0 * 1024 + ln * 64;
    const int gb1 = 0 * 2048 + 1 * 1024 + ln * 64;
    const int gb2 = 1 * 2048 + 0 * 1024 + ln * 64;
    const int gb3 = 1 * 2048 + 1 * 1024 + ln * 64;

#define STAGE_K64(it, buf) do { \
    gload_lds16(Kb + (size_t)(it) * 4096 + t * 8, &Ks[buf][w * 512]); \
    gload_lds16(Kb + (size_t)(it) * 4096 + 2048 + t * 8, &Ks[buf][2048 + w * 512]); } while (0)
#define STAGE_V64(it, buf) do { \
    gload_lds16(Vb + (size_t)(it) * 4096 + t * 8, &Vs[buf][w * 512]); \
    gload_lds16(Vb + (size_t)(it) * 4096 + 2048 + t * 8, &Vs[buf][2048 + w * 512]); } while (0)

    f32x4 acc[4];
#pragma unroll
    for (int i = 0; i < 4; i++) acc[i] = zero;

    float* Arow = attn_out + ((size_t)bh * S + q0 + ln) * S;

    int cur = 0;
    STAGE_K64(0, 0);
    STAGE_V64(0, 0);
    __syncthreads();
    for (int it = 0; it < 32; ++it) {
        if (it < 31) { STAGE_K64(it + 1, cur ^ 1); STAGE_V64(it + 1, cur ^ 1); }
        // pin issue order: the 4 staged loads above must precede the NT stores
        __builtin_amdgcn_sched_barrier(0);
        f32x4 s[4];
        __builtin_amdgcn_s_setprio(1);
        s[0] = MFMA32(*(const short8*)&Ks[cur][gb0 + c0x], qf0, zero);
        s[0] = MFMA32(*(const short8*)&Ks[cur][gb0 + c1x], qf1, s[0]);
        s[1] = MFMA32(*(const short8*)&Ks[cur][gb1 + c0x], qf0, zero);
        s[1] = MFMA32(*(const short8*)&Ks[cur][gb1 + c1x], qf1, s[1]);
        s[2] = MFMA32(*(const short8*)&Ks[cur][gb2 + c0x], qf0, zero);
        s[2] = MFMA32(*(const short8*)&Ks[cur][gb2 + c1x], qf1, s[2]);
        s[3] = MFMA32(*(const short8*)&Ks[cur][gb3 + c0x], qf0, zero);
        s[3] = MFMA32(*(const short8*)&Ks[cur][gb3 + c1x], qf1, s[3]);
        __builtin_amdgcn_s_setprio(0);

        union { short4b v; unsigned int u2[2]; } pf[4];
#pragma unroll
        for (int g = 0; g < 4; g++) {
            f32x4 pw;
#pragma unroll
            for (int j = 0; j < 4; j++)
                pw[j] = exp2f(fmaf(s[g][j], SCL, nlse));
            pf[g].u2[0] = pk_bf16(pw[0], pw[1]);
            pf[g].u2[1] = pk_bf16(pw[2], pw[3]);
            __builtin_nontemporal_store(pw, (f32x4*)&Arow[it * 64 + g * 16 + 4 * lg]);
        }

        __builtin_amdgcn_s_setprio(1);
#pragma unroll
        for (int db = 0; db < 4; db++) {
            int vbase = (db * 16 + ln) * 16 + 4 * lg;
            acc[db] = MFMA_PV(pf[0].v, *(const short4b*)&Vs[cur][0 * 1024 + vbase], acc[db]);
            acc[db] = MFMA_PV(pf[1].v, *(const short4b*)&Vs[cur][1 * 1024 + vbase], acc[db]);
            acc[db] = MFMA_PV(pf[2].v, *(const short4b*)&Vs[cur][2 * 1024 + vbase], acc[db]);
            acc[db] = MFMA_PV(pf[3].v, *(const short4b*)&Vs[cur][3 * 1024 + vbase], acc[db]);
        }
        __builtin_amdgcn_s_setprio(0);
        // counted drain: 4 loads (oldest) must land; 4 NT stores may fly on
        asm volatile("s_waitcnt vmcnt(4)\n\ts_barrier" ::: "memory");
        cur ^= 1;
    }

    // ctx: lane reg j holds (q = q0 + 4*lg + j, d = db*16 + ln)
#pragma unroll
    for (int db = 0; db < 4; db++)
#pragma unroll
        for (int j = 0; j < 4; j++)
            Ctx[(size_t)(b * S + q0 + 4 * lg + j) * Dm + h * 64 + db * 16 + ln] =
                f2bf(acc[db][j]);
#undef STAGE_K64
#undef STAGE_V64
}

// ---------------------------------------------------------------------------
extern "C" void kernel_launch(void* const* d_in, const int* in_sizes, int n_in,
                              void* d_out, int out_size, void* d_ws, size_t ws_size,
                              hipStream_t stream) {
    const float* query = (const float*)d_in[0];
    const float* key_  = (const float*)d_in[1];
    const float* value = (const float*)d_in[2];
    const float* Wq = (const float*)d_in[4];
    const float* bq = (const float*)d_in[5];
    const float* Wk = (const float*)d_in[6];
    const float* bk = (const float*)d_in[7];
    const float* Wv = (const float*)d_in[8];
    const float* bv = (const float*)d_in[9];
    const float* Wo = (const float*)d_in[10];
    const float* bo = (const float*)d_in[11];

    const size_t BSD = (size_t)4 * 2048 * 1024;
    const size_t DD  = (size_t)1024 * 1024;

    unsigned short* Xq  = (unsigned short*)d_ws;
    unsigned short* Xk  = Xq + BSD;
    unsigned short* Xv  = Xk + BSD;
    unsigned short* Qp  = Xv + BSD;
    unsigned short* Kt  = Qp + BSD;                 // K tiled+swizzled
    unsigned short* Vt  = Kt + BSD;                 // V tiled (direct from GEMM)
    unsigned short* WqT = Vt + BSD;
    unsigned short* WkT = WqT + DD;
    unsigned short* WvT = WkT + DD;
    unsigned short* WoT = WvT + DD;
    unsigned short* Ctx = Xq;                       // dead after Q-GEMM

    float* out0 = (float*)d_out;                    // [B,S,D] f32
    float* attn = out0 + BSD;                       // [B,H,S,S] f32

    dim3 tb(256);

    convert3<<<dim3(24576), tb, 0, stream>>>(query, key_, value, Xq, Xk, Xv);
    transpose_w4<<<dim3(32, 32, 4), tb, 0, stream>>>(Wq, Wk, Wv, Wo, WqT, WkT, WvT, WoT);

    gemm_bt<0, 0, 0><<<dim3(8, 64), tb, 0, stream>>>(Xq, WqT, bq, Qp, 8192, 1024, 1024);
    gemm_bt<0, 1, 0><<<dim3(8, 64), tb, 0, stream>>>(Xk, WkT, bk, Kt, 8192, 1024, 1024);
    gemm_bt<0, 0, 1><<<dim3(8, 64), tb, 0, stream>>>(Xv, WvT, bv, Vt, 8192, 1024, 1024);

    attn_fused<<<dim3(2048), tb, 0, stream>>>(Qp, Kt, Vt, attn, Ctx);

    gemm_bt<1, 0, 0><<<dim3(8, 64), tb, 0, stream>>>(Ctx, WoT, bo, out0, 8192, 1024, 1024);
}